// Round 16
// baseline (101.576 us; speedup 1.0000x reference)
//
#include <hip/hip_runtime.h>

#define LL 32
#define MMLEN 3073

// 1/j! for j=0..25  (single-E weights; +1-shifted view = phib weights)
__constant__ float INVF[26] = {
    1.0f, 1.0f, 5.0e-1f, 1.66666672e-1f, 4.16666679e-2f, 8.33333377e-3f,
    1.38888892e-3f, 1.98412701e-4f, 2.48015876e-5f, 2.75573195e-6f,
    2.75573188e-7f, 2.50521089e-8f, 2.08767563e-9f, 1.60590438e-10f,
    1.14707458e-11f, 7.64716373e-13f, 4.77947733e-14f, 2.81145725e-15f,
    1.56192069e-16f, 8.22063525e-18f, 4.11031762e-19f, 1.95729410e-20f,
    8.89679139e-22f, 3.86817017e-23f, 1.61173757e-24f, 6.44695028e-26f};

// 3^j/j! for j=0..28 (+2 zero pads so the one-iteration weight prefetch
// may read wt[N+1..N+2] safely)  — E^3 x = sum_j (3^j/j!) X^j x
__constant__ float INVF3[31] = {
    1.0f, 3.0f, 4.5f, 4.5f, 3.375f, 2.025f, 1.0125f,
    4.33928579e-1f, 1.62723216e-1f, 5.42410724e-2f, 1.62723213e-2f,
    4.43789665e-3f, 1.10947422e-3f, 2.56032491e-4f, 5.48641051e-5f,
    1.09728210e-5f, 2.05740400e-6f, 3.63071287e-7f, 6.05118808e-8f,
    9.55450736e-9f, 1.43317606e-9f, 2.04739441e-10f, 2.79190147e-11f,
    3.64161059e-12f, 4.55201324e-13f, 5.46241588e-14f, 6.30278755e-15f,
    7.00309754e-16f, 7.50331879e-17f, 0.0f, 0.0f};

// trapezoidal pulse, f32 arithmetic replicating the jnp reference
__device__ __forceinline__ float pulsef(float ts) {
    const float rise = 5.0e-10f;
    const float w    = 9.999999999999999e-10f;
    const float e1   = 1.4999999999999998e-9f;
    const float e2   = 1.9999999999999997e-9f;
    const float fall = 5.0e-10f;
    if (ts < rise) return ts / rise;
    if (ts < e1)   return 1.0f;
    if (ts < e2)   return 1.0f - ((ts - w) - rise) / fall;
    return 0.0f;
}

// VALU-pipe cross-lane move (DPP)
template <int CTRL>
__device__ __forceinline__ float dpp_movf(float x) {
    return __int_as_float(__builtin_amdgcn_update_dpp(
        0, __float_as_int(x), CTRL, 0xF, 0xF, true));
}

// ---------------------------------------------------------------------------
// ROUND 16 = round 15 RESUBMITTED UNCHANGED (r15 was an infra failure --
// "container failed twice", no compile error, no verdict; same as r3 which
// ran cleanly on resubmit). Content recap (r14 post-mortem: substep cuts
// stopped converting -- issue/substep constant ~155cy, stall/substep
// DOUBLED -> suspect = exposed per-iteration s_load of weights + tiny
// scheduling window). Three levers:
//   (1) weight SOFTWARE-PREFETCH one iteration ahead (fa_n/fb_n rotation);
//   (2) #pragma unroll 2 on the j-loop (4-substep window; full unroll was
//       r12's 15KB/VGPR-228 disaster, 2x stays ~1KB);
//   (3) trim N: phib/singles 24->18 (tail terms <1e-9 rel at ||X||~2.5),
//       E^3 keeps N=28; rebalance F=34->33:
//         fwd = phib(18) + 11 triples(308)           = 326 substeps
//         bwd = 8 triples(224) -> w_24, 6 singles(108) = 332 substeps
//       (P = sum_{a=25..30} u_{30-a} w_a; 30-k+33 = 63-k exact.)
//
// LANE LAYOUT: lane l = 4*b + q;  b = l>>2 branch, q = l&3 quarter.
// Lane holds chain positions 16q..16q+15, PACKED as pairs (i, i+8):
//   Q[i] = (t[i], t[i+8]), i = 0..7.
// s[p] = al[p]*t[p-1] + be[p]*t[p+1]  ->
//   S[i] = pk_fma(AL[i], Q[i-1], pk_mul(BE[i], Q[i+1]))
// boundary pairs: b0 = (mid-or-halo, Q[7].x), b7 = (Q[0].y, halo).
// Halos are intra-quad quad_perm DPP: zero LDS-pipe ops per substep.
// Mid recurrence: telescoped (r10, verified):
//   m_j = K1*m_{j-2} + R(t_{j-2}),  R(t) = sum_b cM_b*be0_b*t[1]_b.
// ---------------------------------------------------------------------------

typedef unsigned int uint2v __attribute__((ext_vector_type(2)));
typedef float f32x2 __attribute__((ext_vector_type(2)));

// packed f32 ops — compiler-native so the scheduler has full freedom
__device__ __forceinline__ f32x2 pk_fma(f32x2 a, f32x2 b, f32x2 c) {
#if __has_builtin(__builtin_elementwise_fma)
    return __builtin_elementwise_fma(a, b, c);
#else
    f32x2 d;
    asm("v_pk_fma_f32 %0, %1, %2, %3" : "=v"(d) : "v"(a), "v"(b), "v"(c));
    return d;
#endif
}
__device__ __forceinline__ f32x2 pk_mul(f32x2 a, f32x2 b) {
    return a * b;    // fmul <2 x float> -> v_pk_mul_f32
}

// xor-16 / xor-32 all-reduce add, VALU pipe (gfx950 permlane*_swap).
__device__ __forceinline__ float xor16_add(float v) {
#if __has_builtin(__builtin_amdgcn_permlane16_swap)
    uint2v r = __builtin_amdgcn_permlane16_swap(
        __float_as_uint(v), __float_as_uint(v), false, false);
    return __uint_as_float(r.x) + __uint_as_float(r.y);
#else
    return v + __shfl_xor(v, 16);
#endif
}
__device__ __forceinline__ float xor32_add(float v) {
#if __has_builtin(__builtin_amdgcn_permlane32_swap)
    uint2v r = __builtin_amdgcn_permlane32_swap(
        __float_as_uint(v), __float_as_uint(v), false, false);
    return __uint_as_float(r.x) + __uint_as_float(r.y);
#else
    return v + __shfl_xor(v, 32);
#endif
}

// Reduced 64-lane sum for values nonzero ONLY at lanes l%4==0 (branch
// heads). Result valid at all head lanes (the only consumers).
__device__ __forceinline__ float wsum_head(float v) {
    v += dpp_movf<0x124>(v);  // row_ror:4
    v += dpp_movf<0x128>(v);  // row_ror:8 -> row's 4-head sum at head lanes
    v = xor16_add(v);
    v = xor32_add(v);
    return v;
}

// Full 64-lane all-reduce sum (epilogue only).
__device__ __forceinline__ float wave_sum(float v) {
    v += dpp_movf<0xB1>(v);
    v += dpp_movf<0x4E>(v);
    v += dpp_movf<0x124>(v);
    v += dpp_movf<0x128>(v);
    v = xor16_add(v);
    v = xor32_add(v);
    return v;
}

struct ChP {
    f32x2 AL[8]; f32x2 BE[8];
    float cM;    // mid-row coefficient (head lanes only, else 0)
    float cb2;   // cM * be[0]   (head lanes only, else 0)
    float K1;    // sum_b cM_b*al0_b  (valid at head lanes)
};

// One chain substep: S = M*T, WITHOUT the mid reduce (telescoped out).
// mprev = m_{j-1} (consumed by head lanes' b0 only).
__device__ __forceinline__ void sub_chain(const f32x2 (&T)[8], f32x2 (&S)[8],
                                          const ChP& c, float mprev, bool head) {
    const float lv = dpp_movf<0x90>(T[7].y);   // t[15] of q-1
    const float rv = dpp_movf<0xF9>(T[0].x);   // t[0]  of q+1 (q=3: be[15]==0)
    const f32x2 b0 = {head ? mprev : lv, T[7].x};  // (t[-1], t[7])
    const f32x2 b7 = {T[0].y, rv};                 // (t[8],  t[16])
    S[0] = pk_fma(c.AL[0], b0, pk_mul(c.BE[0], T[1]));
#pragma unroll
    for (int i = 1; i < 7; ++i)
        S[i] = pk_fma(c.AL[i], T[i - 1], pk_mul(c.BE[i], T[i + 1]));
    S[7] = pk_fma(c.AL[7], T[6], pk_mul(c.BE[7], b7));
}

// Unified series: X <- (sum_{j<=N} wt[j] X^j) X0, X0 = X (phib=false) or
// e_mid*xm (phib=true: T,X zero-init). wt[0] == 1 for every table used
// (INVF, INVF3, and the phib view INVF+1 whose [0] is INVF[1]=1), so the
// j=0 accumulation is am = xm with no load. N must be even.
// Weights are SOFTWARE-PREFETCHED one iteration ahead (fa_n/fb_n rotation,
// loads issue at iteration top, consumed next iteration) so the s_load
// latency never sits on the critical path; tables are padded so the final
// prefetch (wt[N+1], wt[N+2]) stays in bounds. The j-loop is unrolled 2x
// (4-substep scheduling window; full unroll = r12 front-end disaster).
// Mid pipeline (2-deep, weight-independent): m_j = fmaf(K1, m_{j-2}, Rp),
// Rp = R(t_{j-2}) issued two substeps earlier (r10, verified).
__device__ __forceinline__ void series_u(f32x2 (&X)[8], float& xm,
                                         const ChP& c, bool head,
                                         const float* wt, int N, bool phib) {
    f32x2 T[8], S[8];
    if (phib) {
#pragma unroll
        for (int i = 0; i < 8; ++i) { T[i] = f32x2{0.f, 0.f}; X[i] = f32x2{0.f, 0.f}; }
    } else {
#pragma unroll
        for (int i = 0; i < 8; ++i) T[i] = X[i];
    }
    float am = xm;                          // wt[0] == 1 for all tables used
    float mpp = 0.0f;                       // m_{j-2} (seed m_{-1} = 0)
    float mp  = xm;                         // m_{j-1} (seed m_0)
    float Rp  = wsum_head(c.cM  * T[0].x);  // -> m_1 (direct; K1*0 + Rp)
    float Rq  = wsum_head(c.cb2 * T[1].x);  // R(t_0) -> m_2
    float fa  = wt[1];                      // preload first weight pair
    float fb  = wt[2];
#pragma unroll 2
    for (int j = 1; j + 1 <= N; j += 2) {
        const float fa_n = wt[j + 2];       // prefetch next pair (padded OK)
        const float fb_n = wt[j + 3];
        const f32x2 FA = {fa, fa};
        const f32x2 FB = {fb, fb};
        // ---- substep j: T -> S ----
        const float ma = fmaf(c.K1, mpp, Rp);     // m_j (Rp has 2-substep slack)
        sub_chain(T, S, c, mp, head);
        const float Rna = wsum_head(c.cb2 * S[1].x);  // R(t_j) -> m_{j+2}
#pragma unroll
        for (int i = 0; i < 8; ++i) X[i] = pk_fma(FA, S[i], X[i]);
        am = fmaf(fa, ma, am);
        mpp = mp; mp = ma; Rp = Rq; Rq = Rna;
        // ---- substep j+1: S -> T ----
        const float mb = fmaf(c.K1, mpp, Rp);     // m_{j+1}
        sub_chain(S, T, c, mp, head);
        const float Rnb = wsum_head(c.cb2 * T[1].x);  // R(t_{j+1}) -> m_{j+3}
#pragma unroll
        for (int i = 0; i < 8; ++i) X[i] = pk_fma(FB, T[i], X[i]);
        am = fmaf(fb, mb, am);
        mpp = mp; mp = mb; Rp = Rq; Rq = Rnb;
        fa = fa_n; fb = fb_n;
    }
    xm = am;
}

// coefficients of (A*dt): pos 2k = i[b,k], pos 2k+1 = v[b,k]; packed (i,i+8)
__device__ __forceinline__ void make_fwd(ChP& c, const float* mb,
        const float* gm_c, const float* gm_l, const float* c_val,
        const float* l_val, float swb, float c_mid, float dt,
        int P0i, bool head) {
    float al[16], be[16];
#pragma unroll
    for (int i = 0; i < 16; ++i) {
        int p = P0i + i, k = p >> 1;
        if ((p & 1) == 0) {
            float Lm = 1e-9f * (mb[160 + k] * l_val[k]);
            float a  = dt * ((mb[64 + 2 * k] * gm_l[2 * k]) / Lm);
            if (k == 0) a *= swb;
            al[i] = a;
            be[i] = -dt * ((mb[64 + 2 * k + 1] * gm_l[2 * k + 1]) / Lm);
        } else {
            float C = 1e-9f * (mb[128 + k] * c_val[k]);
            al[i] = dt * ((mb[2 * k] * gm_c[2 * k]) / C);
            be[i] = (k < 31) ? (-dt * ((mb[2 * k + 1] * gm_c[2 * k + 1]) / C))
                             : 0.0f;
        }
    }
#pragma unroll
    for (int i = 0; i < 8; ++i) {
        c.AL[i] = f32x2{al[i], al[i + 8]};
        c.BE[i] = f32x2{be[i], be[i + 8]};
    }
    c.cM  = head ? (-dt * (swb / c_mid)) : 0.0f;
    c.cb2 = c.cM * c.BE[0].x;                  // cM*be[0]; 0 off-head
    c.K1  = wsum_head(c.cM * c.AL[0].x);       // sum_b cM_b*al0_b
}

// transposed coefficients: alT[p] = dt*A[p-1][p], beT[p] = dt*A[p+1][p]
__device__ __forceinline__ void make_bwd(ChP& c, const float* mb,
        const float* gm_c, const float* gm_l, const float* c_val,
        const float* l_val, float swb, float c_mid, float dt,
        int P0i, bool head) {
    float al[16], be[16];
#pragma unroll
    for (int i = 0; i < 16; ++i) {
        int p = P0i + i, k = p >> 1;
        if ((p & 1) == 0) {
            if (p == 0) {
                al[i] = -dt * (swb / c_mid);
            } else {
                float Cm1 = 1e-9f * (mb[128 + (k - 1)] * c_val[k - 1]);
                al[i] = -dt * ((mb[2 * (k - 1) + 1] * gm_c[2 * (k - 1) + 1]) / Cm1);
            }
            float C = 1e-9f * (mb[128 + k] * c_val[k]);
            be[i] = dt * ((mb[2 * k] * gm_c[2 * k]) / C);
        } else {
            float Lm = 1e-9f * (mb[160 + k] * l_val[k]);
            al[i] = -dt * ((mb[64 + 2 * k + 1] * gm_l[2 * k + 1]) / Lm);
            if (k < 31) {
                float Lp1 = 1e-9f * (mb[160 + (k + 1)] * l_val[k + 1]);
                be[i] = dt * ((mb[64 + 2 * (k + 1)] * gm_l[2 * (k + 1)]) / Lp1);
            } else {
                be[i] = 0.0f;
            }
        }
    }
#pragma unroll
    for (int i = 0; i < 8; ++i) {
        c.AL[i] = f32x2{al[i], al[i + 8]};
        c.BE[i] = f32x2{be[i], be[i + 8]};
    }
    float Lm0 = 1e-9f * (mb[160] * l_val[0]);
    c.cM  = head ? (dt * ((swb * (mb[64] * gm_l[0])) / Lm0)) : 0.0f;
    c.cb2 = c.cM * c.BE[0].x;
    c.K1  = wsum_head(c.cM * c.AL[0].x);
}

// Meet-in-the-middle (F=33), one block, 4 waves: wave = 2*star + dir.
// dir 0 (fwd): phib(N=18), then z33 = (E^3)^11 phib  -> LDS
// dir 1 (bwd): w_24 = ((E^T)^3)^8 e_mid, then 6 singles w_25..w_30 (N=18);
//   P = sum_{a=25..30} u_{30-a} w_a  (u_k = pulse((k+0.5)dt), zero for k>=6;
//   verified r4-r14). xm(T) = P . z33.
__global__ __launch_bounds__(256) void sspuf_mitm(
    const int*   __restrict__ swp,
    const float* __restrict__ mismatch,
    const float* __restrict__ gm_c,
    const float* __restrict__ gm_l,
    const float* __restrict__ c_val,
    const float* __restrict__ l_val,
    const float* __restrict__ tp,
    float*       __restrict__ out)
{
    const int tid  = threadIdx.x;
    const int wave = tid >> 6;
    const int star = wave >> 1;
    const bool bwd = wave & 1;
    const int l    = tid & 63;
    const int b    = l >> 2;           // branch
    const int q    = l & 3;            // quarter of the 64-state chain
    const bool head = (q == 0);
    const int P0i  = q << 4;
    const float dt = tp[0] / 64.0f;

    const float* mm = mismatch + star * MMLEN;
    const float* mb = mm + b * 192;
    const float swb   = (float)swp[b];
    const float c_mid = 1e-9f * (mm[MMLEN - 1] * c_val[LL]);

    __shared__ float zbuf[2][1032];    // [star] = z33 (+ mid at [1024])
    __shared__ float partial[2];

    // bwd accumulators (live across the post-barrier epilogue; 17 regs)
    f32x2 PB[8];
    float Pm = 0.0f;
#pragma unroll
    for (int i = 0; i < 8; ++i) PB[i] = f32x2{0.f, 0.f};

    if (!bwd) {
        // ---------------- forward chain ----------------
        ChP c;
        make_fwd(c, mb, gm_c, gm_l, c_val, l_val, swb, c_mid, dt, P0i, head);

        f32x2 Z[8];
        float zm = 1.0f / c_mid;
        series_u(Z, zm, c, head, &INVF[1], 18, true);   // phib series (N=18)
        const f32x2 DT2 = {dt, dt};
#pragma unroll
        for (int i = 0; i < 8; ++i) Z[i] = pk_mul(Z[i], DT2);
        zm *= dt;

#pragma unroll 1
        for (int s = 0; s < 11; ++s)                    // z33 = (E^3)^11 phib
            series_u(Z, zm, c, head, &INVF3[0], 28, false);

#pragma unroll
        for (int i = 0; i < 8; ++i) {
            zbuf[star][l * 16 + i]     = Z[i].x;
            zbuf[star][l * 16 + i + 8] = Z[i].y;
        }
        if (l == 0) zbuf[star][1024] = zm;
    } else {
        // ---------------- backward chain (A^T) ----------------
        ChP c;
        make_bwd(c, mb, gm_c, gm_l, c_val, l_val, swb, c_mid, dt, P0i, head);

        // w_0 = e_mid
        f32x2 W[8];
#pragma unroll
        for (int i = 0; i < 8; ++i) W[i] = f32x2{0.f, 0.f};
        float wm = 1.0f;

#pragma unroll 1
        for (int s = 0; s < 8; ++s)                     // w_24 = ((E^T)^3)^8
            series_u(W, wm, c, head, &INVF3[0], 28, false);

        // 6 singles (N=18) for a = 25..30 (k = 30-a = 5..0), accumulate P
#pragma unroll 1
        for (int a = 25; a <= 30; ++a) {
            series_u(W, wm, c, head, &INVF[0], 18, false);
            const float ub = pulsef(((float)(30 - a) + 0.5f) * dt);
            const f32x2 UB2 = {ub, ub};
#pragma unroll
            for (int i = 0; i < 8; ++i) PB[i] = pk_fma(UB2, W[i], PB[i]);
            Pm = fmaf(ub, wm, Pm);
        }
    }

    __syncthreads();

    if (bwd) {
        float part = 0.0f;
#pragma unroll
        for (int i = 0; i < 8; ++i)
            part += PB[i].x * zbuf[star][l * 16 + i]
                  + PB[i].y * zbuf[star][l * 16 + i + 8];
        if (l == 0)
            part += Pm * zbuf[star][1024];
        part = wave_sum(part);
        if (l == 0) partial[star] = part;
    }

    __syncthreads();
    if (tid == 0) out[0] = partial[0] - partial[1];
}

extern "C" void kernel_launch(void* const* d_in, const int* in_sizes, int n_in,
                              void* d_out, int out_size, void* d_ws, size_t ws_size,
                              hipStream_t stream) {
    const int*   swp      = (const int*)d_in[0];
    const float* mismatch = (const float*)d_in[1];
    const float* gm_c     = (const float*)d_in[2];
    const float* gm_l     = (const float*)d_in[3];
    const float* c_val    = (const float*)d_in[4];
    const float* l_val    = (const float*)d_in[5];
    const float* tp       = (const float*)d_in[6];
    float* out = (float*)d_out;

    sspuf_mitm<<<dim3(1), dim3(256), 0, stream>>>(
        swp, mismatch, gm_c, gm_l, c_val, l_val, tp, out);
}

// Round 17
// 100.827 us; speedup vs baseline: 1.0074x; 1.0074x over previous
//
#include <hip/hip_runtime.h>

#define LL 32
#define MMLEN 3073

// 1/j! for j=0..25  (single-E weights; +1-shifted view = phib weights)
__constant__ float INVF[26] = {
    1.0f, 1.0f, 5.0e-1f, 1.66666672e-1f, 4.16666679e-2f, 8.33333377e-3f,
    1.38888892e-3f, 1.98412701e-4f, 2.48015876e-5f, 2.75573195e-6f,
    2.75573188e-7f, 2.50521089e-8f, 2.08767563e-9f, 1.60590438e-10f,
    1.14707458e-11f, 7.64716373e-13f, 4.77947733e-14f, 2.81145725e-15f,
    1.56192069e-16f, 8.22063525e-18f, 4.11031762e-19f, 1.95729410e-20f,
    8.89679139e-22f, 3.86817017e-23f, 1.61173757e-24f, 6.44695028e-26f};

// 2^j/j! for j=0..30  (double-step weights; kept for flexibility)
__constant__ float INVF2[31] = {
    1.0f, 2.0f, 2.0f, 1.33333337f, 6.66666687e-1f, 2.66666681e-1f,
    8.88888910e-2f, 2.53968258e-2f, 6.34920632e-3f, 1.41093472e-3f,
    2.82186945e-4f, 5.13067183e-5f, 8.55111971e-6f, 1.31555690e-6f,
    1.87936698e-7f, 2.50582261e-8f, 3.13227831e-9f, 3.68503328e-10f,
    4.09448147e-11f, 4.30998052e-12f, 4.30998052e-13f, 4.10474333e-14f,
    3.73158482e-15f, 3.24485639e-16f, 2.70404699e-17f, 2.16323759e-18f,
    1.66402891e-19f, 1.23261403e-20f, 8.80438581e-22f, 6.07205918e-23f,
    4.04803945e-24f};

// 3^j/j! for j=0..28  (triple-step weights: E^3 x = sum_j (3^j/j!) X^j x)
__constant__ float INVF3[29] = {
    1.0f, 3.0f, 4.5f, 4.5f, 3.375f, 2.025f, 1.0125f,
    4.33928579e-1f, 1.62723216e-1f, 5.42410724e-2f, 1.62723213e-2f,
    4.43789665e-3f, 1.10947422e-3f, 2.56032491e-4f, 5.48641051e-5f,
    1.09728210e-5f, 2.05740400e-6f, 3.63071287e-7f, 6.05118808e-8f,
    9.55450736e-9f, 1.43317606e-9f, 2.04739441e-10f, 2.79190147e-11f,
    3.64161059e-12f, 4.55201324e-13f, 5.46241588e-14f, 6.30278755e-15f,
    7.00309754e-16f, 7.50331879e-17f};

// trapezoidal pulse, f32 arithmetic replicating the jnp reference
__device__ __forceinline__ float pulsef(float ts) {
    const float rise = 5.0e-10f;
    const float w    = 9.999999999999999e-10f;
    const float e1   = 1.4999999999999998e-9f;
    const float e2   = 1.9999999999999997e-9f;
    const float fall = 5.0e-10f;
    if (ts < rise) return ts / rise;
    if (ts < e1)   return 1.0f;
    if (ts < e2)   return 1.0f - ((ts - w) - rise) / fall;
    return 0.0f;
}

// VALU-pipe cross-lane move (DPP)
template <int CTRL>
__device__ __forceinline__ float dpp_movf(float x) {
    return __int_as_float(__builtin_amdgcn_update_dpp(
        0, __float_as_int(x), CTRL, 0xF, 0xF, true));
}

// ---------------------------------------------------------------------------
// ROUND 17 = CLEAN REVERT to round 14 (best measured: 56.6us dispatch,
// 80 VGPR, absmax 0.0). Round 16's bundle (weight prefetch + unroll 2 +
// N-trim) REGRESSED to 74.5us with VGPR 80->176 and per-CU VALUBusy
// 41%->31% -- the r12 code-bloat signature in miniature. Conclusion from
// r13->r14 (flat under -30% substeps) + r16 (worse under window widening):
// the tight VGPR-80 2-substep loop is a sticky local optimum; residual
// stall is intrinsic dependent/DPP-hazard latency at 1 wave/SIMD (plus a
// possible 1-CU clock-ramp floor), not addressable by unroll/prefetch/
// substep-count levers (all now tested both directions).
//
// Kernel content = r14: triple-step E^3 batching, F=34 MITM split:
//   fwd = phib(24) + 11 triples(308) + 1 single(24) = 356 substeps
//   bwd = 8 triples(224) -> w_24, + 5 singles(120)  = 344 substeps
//
// LANE LAYOUT: lane l = 4*b + q;  b = l>>2 branch, q = l&3 quarter.
// Lane holds chain positions 16q..16q+15, PACKED as pairs (i, i+8):
//   Q[i] = (t[i], t[i+8]), i = 0..7.
// s[p] = al[p]*t[p-1] + be[p]*t[p+1]  ->
//   S[i] = pk_fma(AL[i], Q[i-1], pk_mul(BE[i], Q[i+1]))
// boundary pairs: b0 = (mid-or-halo, Q[7].x), b7 = (Q[0].y, halo).
// Halos are intra-quad quad_perm DPP: zero LDS-pipe ops per substep.
// Mid recurrence: telescoped (r10, verified):
//   m_j = K1*m_{j-2} + R(t_{j-2}),  R(t) = sum_b cM_b*be0_b*t[1]_b.
// ---------------------------------------------------------------------------

typedef unsigned int uint2v __attribute__((ext_vector_type(2)));
typedef float f32x2 __attribute__((ext_vector_type(2)));

// packed f32 ops — compiler-native so the scheduler has full freedom
__device__ __forceinline__ f32x2 pk_fma(f32x2 a, f32x2 b, f32x2 c) {
#if __has_builtin(__builtin_elementwise_fma)
    return __builtin_elementwise_fma(a, b, c);
#else
    f32x2 d;
    asm("v_pk_fma_f32 %0, %1, %2, %3" : "=v"(d) : "v"(a), "v"(b), "v"(c));
    return d;
#endif
}
__device__ __forceinline__ f32x2 pk_mul(f32x2 a, f32x2 b) {
    return a * b;    // fmul <2 x float> -> v_pk_mul_f32
}

// xor-16 / xor-32 all-reduce add, VALU pipe (gfx950 permlane*_swap).
__device__ __forceinline__ float xor16_add(float v) {
#if __has_builtin(__builtin_amdgcn_permlane16_swap)
    uint2v r = __builtin_amdgcn_permlane16_swap(
        __float_as_uint(v), __float_as_uint(v), false, false);
    return __uint_as_float(r.x) + __uint_as_float(r.y);
#else
    return v + __shfl_xor(v, 16);
#endif
}
__device__ __forceinline__ float xor32_add(float v) {
#if __has_builtin(__builtin_amdgcn_permlane32_swap)
    uint2v r = __builtin_amdgcn_permlane32_swap(
        __float_as_uint(v), __float_as_uint(v), false, false);
    return __uint_as_float(r.x) + __uint_as_float(r.y);
#else
    return v + __shfl_xor(v, 32);
#endif
}

// Reduced 64-lane sum for values nonzero ONLY at lanes l%4==0 (branch
// heads). Result valid at all head lanes (the only consumers).
__device__ __forceinline__ float wsum_head(float v) {
    v += dpp_movf<0x124>(v);  // row_ror:4
    v += dpp_movf<0x128>(v);  // row_ror:8 -> row's 4-head sum at head lanes
    v = xor16_add(v);
    v = xor32_add(v);
    return v;
}

// Full 64-lane all-reduce sum (epilogue only).
__device__ __forceinline__ float wave_sum(float v) {
    v += dpp_movf<0xB1>(v);
    v += dpp_movf<0x4E>(v);
    v += dpp_movf<0x124>(v);
    v += dpp_movf<0x128>(v);
    v = xor16_add(v);
    v = xor32_add(v);
    return v;
}

struct ChP {
    f32x2 AL[8]; f32x2 BE[8];
    float cM;    // mid-row coefficient (head lanes only, else 0)
    float cb2;   // cM * be[0]   (head lanes only, else 0)
    float K1;    // sum_b cM_b*al0_b  (valid at head lanes)
};

// One chain substep: S = M*T, WITHOUT the mid reduce (telescoped out).
// mprev = m_{j-1} (consumed by head lanes' b0 only).
__device__ __forceinline__ void sub_chain(const f32x2 (&T)[8], f32x2 (&S)[8],
                                          const ChP& c, float mprev, bool head) {
    const float lv = dpp_movf<0x90>(T[7].y);   // t[15] of q-1
    const float rv = dpp_movf<0xF9>(T[0].x);   // t[0]  of q+1 (q=3: be[15]==0)
    const f32x2 b0 = {head ? mprev : lv, T[7].x};  // (t[-1], t[7])
    const f32x2 b7 = {T[0].y, rv};                 // (t[8],  t[16])
    S[0] = pk_fma(c.AL[0], b0, pk_mul(c.BE[0], T[1]));
#pragma unroll
    for (int i = 1; i < 7; ++i)
        S[i] = pk_fma(c.AL[i], T[i - 1], pk_mul(c.BE[i], T[i + 1]));
    S[7] = pk_fma(c.AL[7], T[6], pk_mul(c.BE[7], b7));
}

// Unified series: X <- (sum_{j<=N} wt[j] X^j) X0, X0 = X (phib=false) or
// e_mid*xm (phib=true: T,X zero-init; am0=wt[0]*xm covers both cases since
// wt[0]=1 for INVF/INVF2/INVF3 and =INVF[1] for INVF+1). N must be even.
// Weights from __constant__ memory (wave-uniform s_load, latency-hidden);
// the j-loop is NOT unrolled, keeping code footprint ~2 substeps (r12's
// full unroll and r16's unroll-2+prefetch both regressed: VGPR bloat,
// front-end/scheduling loss. The tight loop is the measured optimum).
// Mid pipeline (2-deep, weight-independent): m_j = fmaf(K1, m_{j-2}, Rp),
// Rp = R(t_{j-2}) issued two substeps earlier (r10, verified).
__device__ __forceinline__ void series_u(f32x2 (&X)[8], float& xm,
                                         const ChP& c, bool head,
                                         const float* wt, int N, bool phib) {
    f32x2 T[8], S[8];
    if (phib) {
#pragma unroll
        for (int i = 0; i < 8; ++i) { T[i] = f32x2{0.f, 0.f}; X[i] = f32x2{0.f, 0.f}; }
    } else {
#pragma unroll
        for (int i = 0; i < 8; ++i) T[i] = X[i];
    }
    float am = wt[0] * xm;
    float mpp = 0.0f;                       // m_{j-2} (seed m_{-1} = 0)
    float mp  = xm;                         // m_{j-1} (seed m_0)
    float Rp  = wsum_head(c.cM  * T[0].x);  // -> m_1 (direct; K1*0 + Rp)
    float Rq  = wsum_head(c.cb2 * T[1].x);  // R(t_0) -> m_2
#pragma unroll 1
    for (int j = 1; j + 1 <= N; j += 2) {
        const float fa = wt[j];
        const float fb = wt[j + 1];
        const f32x2 FA = {fa, fa};
        const f32x2 FB = {fb, fb};
        // ---- substep j: T -> S ----
        const float ma = fmaf(c.K1, mpp, Rp);     // m_j (Rp has 2-substep slack)
        sub_chain(T, S, c, mp, head);
        const float Rna = wsum_head(c.cb2 * S[1].x);  // R(t_j) -> m_{j+2}
#pragma unroll
        for (int i = 0; i < 8; ++i) X[i] = pk_fma(FA, S[i], X[i]);
        am = fmaf(fa, ma, am);
        mpp = mp; mp = ma; Rp = Rq; Rq = Rna;
        // ---- substep j+1: S -> T ----
        const float mb = fmaf(c.K1, mpp, Rp);     // m_{j+1}
        sub_chain(S, T, c, mp, head);
        const float Rnb = wsum_head(c.cb2 * T[1].x);  // R(t_{j+1}) -> m_{j+3}
#pragma unroll
        for (int i = 0; i < 8; ++i) X[i] = pk_fma(FB, T[i], X[i]);
        am = fmaf(fb, mb, am);
        mpp = mp; mp = mb; Rp = Rq; Rq = Rnb;
    }
    xm = am;
}

// coefficients of (A*dt): pos 2k = i[b,k], pos 2k+1 = v[b,k]; packed (i,i+8)
__device__ __forceinline__ void make_fwd(ChP& c, const float* mb,
        const float* gm_c, const float* gm_l, const float* c_val,
        const float* l_val, float swb, float c_mid, float dt,
        int P0i, bool head) {
    float al[16], be[16];
#pragma unroll
    for (int i = 0; i < 16; ++i) {
        int p = P0i + i, k = p >> 1;
        if ((p & 1) == 0) {
            float Lm = 1e-9f * (mb[160 + k] * l_val[k]);
            float a  = dt * ((mb[64 + 2 * k] * gm_l[2 * k]) / Lm);
            if (k == 0) a *= swb;
            al[i] = a;
            be[i] = -dt * ((mb[64 + 2 * k + 1] * gm_l[2 * k + 1]) / Lm);
        } else {
            float C = 1e-9f * (mb[128 + k] * c_val[k]);
            al[i] = dt * ((mb[2 * k] * gm_c[2 * k]) / C);
            be[i] = (k < 31) ? (-dt * ((mb[2 * k + 1] * gm_c[2 * k + 1]) / C))
                             : 0.0f;
        }
    }
#pragma unroll
    for (int i = 0; i < 8; ++i) {
        c.AL[i] = f32x2{al[i], al[i + 8]};
        c.BE[i] = f32x2{be[i], be[i + 8]};
    }
    c.cM  = head ? (-dt * (swb / c_mid)) : 0.0f;
    c.cb2 = c.cM * c.BE[0].x;                  // cM*be[0]; 0 off-head
    c.K1  = wsum_head(c.cM * c.AL[0].x);       // sum_b cM_b*al0_b
}

// transposed coefficients: alT[p] = dt*A[p-1][p], beT[p] = dt*A[p+1][p]
__device__ __forceinline__ void make_bwd(ChP& c, const float* mb,
        const float* gm_c, const float* gm_l, const float* c_val,
        const float* l_val, float swb, float c_mid, float dt,
        int P0i, bool head) {
    float al[16], be[16];
#pragma unroll
    for (int i = 0; i < 16; ++i) {
        int p = P0i + i, k = p >> 1;
        if ((p & 1) == 0) {
            if (p == 0) {
                al[i] = -dt * (swb / c_mid);
            } else {
                float Cm1 = 1e-9f * (mb[128 + (k - 1)] * c_val[k - 1]);
                al[i] = -dt * ((mb[2 * (k - 1) + 1] * gm_c[2 * (k - 1) + 1]) / Cm1);
            }
            float C = 1e-9f * (mb[128 + k] * c_val[k]);
            be[i] = dt * ((mb[2 * k] * gm_c[2 * k]) / C);
        } else {
            float Lm = 1e-9f * (mb[160 + k] * l_val[k]);
            al[i] = -dt * ((mb[64 + 2 * k + 1] * gm_l[2 * k + 1]) / Lm);
            if (k < 31) {
                float Lp1 = 1e-9f * (mb[160 + (k + 1)] * l_val[k + 1]);
                be[i] = dt * ((mb[64 + 2 * (k + 1)] * gm_l[2 * (k + 1)]) / Lp1);
            } else {
                be[i] = 0.0f;
            }
        }
    }
#pragma unroll
    for (int i = 0; i < 8; ++i) {
        c.AL[i] = f32x2{al[i], al[i + 8]};
        c.BE[i] = f32x2{be[i], be[i + 8]};
    }
    float Lm0 = 1e-9f * (mb[160] * l_val[0]);
    c.cM  = head ? (dt * ((swb * (mb[64] * gm_l[0])) / Lm0)) : 0.0f;
    c.cb2 = c.cM * c.BE[0].x;
    c.K1  = wsum_head(c.cM * c.AL[0].x);
}

// Meet-in-the-middle (F=34), one block, 4 waves: wave = 2*star + dir.
// dir 0 (fwd): phib, then z34 = E^34 phib = (E^3)^11 E phib  -> LDS
// dir 1 (bwd): w_24 = ((E^T)^3)^8 e_mid, then 5 singles w_25..w_29;
//   P = sum_{a=24..29} u_{29-a} w_a  (u_k = pulse((k+0.5)dt), zero for k>=6;
//   u_5 = 0.5625 fall-edge .. u_0 = 0.3125 rise-edge). xm(T) = P . z34.
__global__ __launch_bounds__(256) void sspuf_mitm(
    const int*   __restrict__ swp,
    const float* __restrict__ mismatch,
    const float* __restrict__ gm_c,
    const float* __restrict__ gm_l,
    const float* __restrict__ c_val,
    const float* __restrict__ l_val,
    const float* __restrict__ tp,
    float*       __restrict__ out)
{
    const int tid  = threadIdx.x;
    const int wave = tid >> 6;
    const int star = wave >> 1;
    const bool bwd = wave & 1;
    const int l    = tid & 63;
    const int b    = l >> 2;           // branch
    const int q    = l & 3;            // quarter of the 64-state chain
    const bool head = (q == 0);
    const int P0i  = q << 4;
    const float dt = tp[0] / 64.0f;

    const float* mm = mismatch + star * MMLEN;
    const float* mb = mm + b * 192;
    const float swb   = (float)swp[b];
    const float c_mid = 1e-9f * (mm[MMLEN - 1] * c_val[LL]);

    __shared__ float zbuf[2][1032];    // [star] = z34 (+ mid at [1024])
    __shared__ float partial[2];

    // bwd accumulators (live across the post-barrier epilogue; 17 regs)
    f32x2 PB[8];
    float Pm = 0.0f;
#pragma unroll
    for (int i = 0; i < 8; ++i) PB[i] = f32x2{0.f, 0.f};

    if (!bwd) {
        // ---------------- forward chain ----------------
        ChP c;
        make_fwd(c, mb, gm_c, gm_l, c_val, l_val, swb, c_mid, dt, P0i, head);

        f32x2 Z[8];
        float zm = 1.0f / c_mid;
        series_u(Z, zm, c, head, &INVF[1], 24, true);   // phib series
        const f32x2 DT2 = {dt, dt};
#pragma unroll
        for (int i = 0; i < 8; ++i) Z[i] = pk_mul(Z[i], DT2);
        zm *= dt;

#pragma unroll 1
        for (int s = 0; s < 11; ++s)                    // (E^3)^11 = E^33
            series_u(Z, zm, c, head, &INVF3[0], 28, false);
        series_u(Z, zm, c, head, &INVF[0], 24, false);  // +1 single -> E^34

#pragma unroll
        for (int i = 0; i < 8; ++i) {
            zbuf[star][l * 16 + i]     = Z[i].x;
            zbuf[star][l * 16 + i + 8] = Z[i].y;
        }
        if (l == 0) zbuf[star][1024] = zm;
    } else {
        // ---------------- backward chain (A^T) ----------------
        ChP c;
        make_bwd(c, mb, gm_c, gm_l, c_val, l_val, swb, c_mid, dt, P0i, head);

        // w_0 = e_mid
        f32x2 W[8];
#pragma unroll
        for (int i = 0; i < 8; ++i) W[i] = f32x2{0.f, 0.f};
        float wm = 1.0f;

#pragma unroll 1
        for (int s = 0; s < 8; ++s)                     // w_24 = ((E^T)^3)^8
            series_u(W, wm, c, head, &INVF3[0], 28, false);

        // accumulate a = 24 (k=5), then 5 singles for a = 25..29 (k=4..0)
#pragma unroll 1
        for (int a = 24; a <= 29; ++a) {
            if (a > 24) series_u(W, wm, c, head, &INVF[0], 24, false);
            const float ub = pulsef(((float)(29 - a) + 0.5f) * dt);
            const f32x2 UB2 = {ub, ub};
#pragma unroll
            for (int i = 0; i < 8; ++i) PB[i] = pk_fma(UB2, W[i], PB[i]);
            Pm = fmaf(ub, wm, Pm);
        }
    }

    __syncthreads();

    if (bwd) {
        float part = 0.0f;
#pragma unroll
        for (int i = 0; i < 8; ++i)
            part += PB[i].x * zbuf[star][l * 16 + i]
                  + PB[i].y * zbuf[star][l * 16 + i + 8];
        if (l == 0)
            part += Pm * zbuf[star][1024];
        part = wave_sum(part);
        if (l == 0) partial[star] = part;
    }

    __syncthreads();
    if (tid == 0) out[0] = partial[0] - partial[1];
}

extern "C" void kernel_launch(void* const* d_in, const int* in_sizes, int n_in,
                              void* d_out, int out_size, void* d_ws, size_t ws_size,
                              hipStream_t stream) {
    const int*   swp      = (const int*)d_in[0];
    const float* mismatch = (const float*)d_in[1];
    const float* gm_c     = (const float*)d_in[2];
    const float* gm_l     = (const float*)d_in[3];
    const float* c_val    = (const float*)d_in[4];
    const float* l_val    = (const float*)d_in[5];
    const float* tp       = (const float*)d_in[6];
    float* out = (float*)d_out;

    sspuf_mitm<<<dim3(1), dim3(256), 0, stream>>>(
        swp, mismatch, gm_c, gm_l, c_val, l_val, tp, out);
}